// Round 1
// 347.874 us; speedup vs baseline: 1.0027x; 1.0027x over previous
//
#include <hip/hip_runtime.h>
#include <hip/hip_bf16.h>

#define D_DIM 768
#define F_DIM 16384
#define M_CONN 262144
#define N_ROWS 1024   // B*S = 2*512

__device__ __forceinline__ float bf2f(unsigned short u) {
    return __uint_as_float(((unsigned int)u) << 16);
}

// ---------------------------------------------------------------------------
// Vectorized fp32 -> fp32 transpose: in [R][C] -> out [C][R].
// 64x64 tile, 256 threads. Loads float4 (16B/lane), stores float4 (16B/lane).
// LDS [64][66]: float2 writes (8B aligned), scalar reads (<=4-way conflict,
// LDS is ~5x off the global-BW critical path so this is fine).
// Grid: dim3(C/64, R/64).
// ---------------------------------------------------------------------------
__global__ __launch_bounds__(256) void transpose_v4(const float* __restrict__ in,
                                                    float* __restrict__ out,
                                                    int R, int C) {
    __shared__ float tile[64][66];
    const int t = threadIdx.x;
    const int x0 = blockIdx.x * 64;  // col origin in `in`
    const int y0 = blockIdx.y * 64;  // row origin in `in`
#pragma unroll
    for (int k = 0; k < 4; ++k) {
        const int idx = k * 256 + t;
        const int r = idx >> 4, c4 = idx & 15;
        const float4 v = *(const float4*)(in + (size_t)(y0 + r) * C + x0 + c4 * 4);
        float* p = &tile[r][c4 * 4];
        *(float2*)(p)     = make_float2(v.x, v.y);
        *(float2*)(p + 2) = make_float2(v.z, v.w);
    }
    __syncthreads();
#pragma unroll
    for (int k = 0; k < 4; ++k) {
        const int idx = k * 256 + t;
        const int c = idx >> 4, r4 = idx & 15;  // out row = x0+c, out cols y0+4r4..+3
        float4 o;
        o.x = tile[r4 * 4 + 0][c];
        o.y = tile[r4 * 4 + 1][c];
        o.z = tile[r4 * 4 + 2][c];
        o.w = tile[r4 * 4 + 3][c];
        *(float4*)(out + (size_t)(x0 + c) * R + y0 + r4 * 4) = o;
    }
}

// ---------------------------------------------------------------------------
// Vectorized fp32 -> bf16 transpose: in [R][C] fp32 -> out [C][R] bf16.
// Same structure; stores ushort4 (8B/lane, 4 packed bf16). RNE conversion
// identical to the previous version (bitwise-same results).
// Grid: dim3(C/64, R/64).
// ---------------------------------------------------------------------------
__global__ __launch_bounds__(256) void transpose_f2b_v4(const float* __restrict__ in,
                                                        unsigned short* __restrict__ out,
                                                        int R, int C) {
    __shared__ float tile[64][66];
    const int t = threadIdx.x;
    const int x0 = blockIdx.x * 64;
    const int y0 = blockIdx.y * 64;
#pragma unroll
    for (int k = 0; k < 4; ++k) {
        const int idx = k * 256 + t;
        const int r = idx >> 4, c4 = idx & 15;
        const float4 v = *(const float4*)(in + (size_t)(y0 + r) * C + x0 + c4 * 4);
        float* p = &tile[r][c4 * 4];
        *(float2*)(p)     = make_float2(v.x, v.y);
        *(float2*)(p + 2) = make_float2(v.z, v.w);
    }
    __syncthreads();
#pragma unroll
    for (int k = 0; k < 4; ++k) {
        const int idx = k * 256 + t;
        const int c = idx >> 4, r4 = idx & 15;
        __hip_bfloat16 b0 = __float2bfloat16(tile[r4 * 4 + 0][c]);
        __hip_bfloat16 b1 = __float2bfloat16(tile[r4 * 4 + 1][c]);
        __hip_bfloat16 b2 = __float2bfloat16(tile[r4 * 4 + 2][c]);
        __hip_bfloat16 b3 = __float2bfloat16(tile[r4 * 4 + 3][c]);
        ushort4 o;
        o.x = *(unsigned short*)&b0;
        o.y = *(unsigned short*)&b1;
        o.z = *(unsigned short*)&b2;
        o.w = *(unsigned short*)&b3;
        *(ushort4*)(out + (size_t)(x0 + c) * R + y0 + r4 * 4) = o;
    }
}

// ---------------------------------------------------------------------------
// values[m] = dot(de[i_m, :], udT[j_m, :]) over D=768, udT in bf16.
// One wave per 4 consecutive m; sorted i -> de row register-cached across m.
// ---------------------------------------------------------------------------
__global__ __launch_bounds__(256) void values_kernel(const float* __restrict__ de,
                                                     const unsigned short* __restrict__ udT,
                                                     const int* __restrict__ i_idx,
                                                     const int* __restrict__ j_idx,
                                                     float* __restrict__ values) {
    const int wave = (blockIdx.x * blockDim.x + threadIdx.x) >> 6;
    const int lane = threadIdx.x & 63;
    const int mbase = wave * 4;
    int cur_i = -1;
    float4 a0, a1, a2;
#pragma unroll
    for (int t = 0; t < 4; ++t) {
        const int m = mbase + t;
        const int i = i_idx[m];
        const int j = j_idx[m];
        if (i != cur_i) {  // wave-uniform (i uniform across lanes)
            const float4* a = (const float4*)(de + (size_t)i * D_DIM);
            a0 = a[lane]; a1 = a[lane + 64]; a2 = a[lane + 128];
            cur_i = i;
        }
        const ushort4* b = (const ushort4*)(udT + (size_t)j * D_DIM);
        ushort4 u0 = b[lane], u1 = b[lane + 64], u2 = b[lane + 128];
        float s = 0.f;
        s = fmaf(a0.x, bf2f(u0.x), s); s = fmaf(a0.y, bf2f(u0.y), s);
        s = fmaf(a0.z, bf2f(u0.z), s); s = fmaf(a0.w, bf2f(u0.w), s);
        s = fmaf(a1.x, bf2f(u1.x), s); s = fmaf(a1.y, bf2f(u1.y), s);
        s = fmaf(a1.z, bf2f(u1.z), s); s = fmaf(a1.w, bf2f(u1.w), s);
        s = fmaf(a2.x, bf2f(u2.x), s); s = fmaf(a2.y, bf2f(u2.y), s);
        s = fmaf(a2.z, bf2f(u2.z), s); s = fmaf(a2.w, bf2f(u2.w), s);
#pragma unroll
        for (int off = 32; off > 0; off >>= 1)
            s += __shfl_down(s, off, 64);
        if (lane == 0) values[m] = s;
    }
}

// ---------------------------------------------------------------------------
// seg[i] = lower_bound(i_idx, M, i); seg[F] = M.
// ---------------------------------------------------------------------------
__global__ __launch_bounds__(256) void seg_kernel(const int* __restrict__ i_idx,
                                                  int* __restrict__ seg) {
    const int i = blockIdx.x * blockDim.x + threadIdx.x;
    if (i > F_DIM) return;
    if (i == F_DIM) { seg[i] = M_CONN; return; }
    int lo = 0, hi = M_CONN;
    while (lo < hi) {
        int mid = (lo + hi) >> 1;
        if (i_idx[mid] < i) lo = mid + 1; else hi = mid;
    }
    seg[i] = lo;
}

// ---------------------------------------------------------------------------
// SpMM, transposed layout, bf16 rows: outT[i,:] = sum_m v_m * upT[j_m,:].
// One 256-thread block per i; 4 bf16 (8B) per thread per connection; fp32 acc.
// ---------------------------------------------------------------------------
__global__ __launch_bounds__(256) void spmm_kernel(const unsigned short* __restrict__ upT,
                                                   const int* __restrict__ j_idx,
                                                   const float* __restrict__ vals,
                                                   const int* __restrict__ seg,
                                                   float* __restrict__ outT) {
    const int i = blockIdx.x;
    const int t = threadIdx.x;
    const int ms = seg[i], me = seg[i + 1];
    float4 acc0 = make_float4(0.f, 0.f, 0.f, 0.f);
    float4 acc1 = make_float4(0.f, 0.f, 0.f, 0.f);
    int m = ms;
    for (; m + 1 < me; m += 2) {
        const int j0 = j_idx[m], j1 = j_idx[m + 1];
        const float v0 = vals[m], v1 = vals[m + 1];
        const ushort4 x0 = ((const ushort4*)(upT + (size_t)j0 * N_ROWS))[t];
        const ushort4 x1 = ((const ushort4*)(upT + (size_t)j1 * N_ROWS))[t];
        acc0.x = fmaf(v0, bf2f(x0.x), acc0.x); acc0.y = fmaf(v0, bf2f(x0.y), acc0.y);
        acc0.z = fmaf(v0, bf2f(x0.z), acc0.z); acc0.w = fmaf(v0, bf2f(x0.w), acc0.w);
        acc1.x = fmaf(v1, bf2f(x1.x), acc1.x); acc1.y = fmaf(v1, bf2f(x1.y), acc1.y);
        acc1.z = fmaf(v1, bf2f(x1.z), acc1.z); acc1.w = fmaf(v1, bf2f(x1.w), acc1.w);
    }
    if (m < me) {
        const int j0 = j_idx[m];
        const float v0 = vals[m];
        const ushort4 x0 = ((const ushort4*)(upT + (size_t)j0 * N_ROWS))[t];
        acc0.x = fmaf(v0, bf2f(x0.x), acc0.x); acc0.y = fmaf(v0, bf2f(x0.y), acc0.y);
        acc0.z = fmaf(v0, bf2f(x0.z), acc0.z); acc0.w = fmaf(v0, bf2f(x0.w), acc0.w);
    }
    acc0.x += acc1.x; acc0.y += acc1.y; acc0.z += acc1.z; acc0.w += acc1.w;
    ((float4*)(outT + (size_t)i * N_ROWS))[t] = acc0;
}

// ---------------------------------------------------------------------------
// Buffer plan (ws ~65.1 MB):
//   ws + 0     : udT bf16 [F,D] 24 MB (stages 1-2), then outT fp32 [F,1024] 64 MB
//   ws + 64 MB : values [M] fp32, 1 MB
//   ws + 65 MB : seg [F+1] int, 64 KB
//   d_out      : upT bf16 [F,1024] 32 MB (stages 3-5), then final out fp32
// ---------------------------------------------------------------------------
extern "C" void kernel_launch(void* const* d_in, const int* in_sizes, int n_in,
                              void* d_out, int out_size, void* d_ws, size_t ws_size,
                              hipStream_t stream) {
    const float* up_facts = (const float*)d_in[0];   // [1024, F]
    const float* de       = (const float*)d_in[1];   // [F, D]
    const float* ud       = (const float*)d_in[2];   // [D, F]
    const int*   i_idx    = (const int*)d_in[3];     // [M] sorted
    const int*   j_idx    = (const int*)d_in[4];     // [M]
    float* out = (float*)d_out;

    char* ws = (char*)d_ws;
    unsigned short* udT = (unsigned short*)ws;                     // bf16 [F, D]
    float* outT   = (float*)ws;                                    // fp32 [F, 1024] (udT dead)
    float* values = (float*)(ws + (size_t)64 * 1024 * 1024);       // 1 MB
    int*   seg    = (int*)  (ws + (size_t)65 * 1024 * 1024);       // 64 KB + 4
    unsigned short* upT = (unsigned short*)out;                    // bf16 [F, 1024]

    // 1) udT = bf16(ud^T): in [768][16384] -> out [16384][768]
    transpose_f2b_v4<<<dim3(F_DIM / 64, D_DIM / 64), 256, 0, stream>>>(
        ud, udT, D_DIM, F_DIM);
    // 2) values[m] = <de[i_m], udT[j_m]>
    values_kernel<<<(M_CONN / 4) * 64 / 256, 256, 0, stream>>>(de, udT, i_idx, j_idx, values);
    // 3) upT = bf16(up_facts^T): in [1024][16384] -> out [16384][1024]
    transpose_f2b_v4<<<dim3(F_DIM / 64, N_ROWS / 64), 256, 0, stream>>>(
        up_facts, upT, N_ROWS, F_DIM);
    // 4) CSR row pointers
    seg_kernel<<<(F_DIM + 1 + 255) / 256, 256, 0, stream>>>(i_idx, seg);
    // 5) outT[i] = sum v * upT[j]
    spmm_kernel<<<F_DIM, 256, 0, stream>>>(upT, j_idx, values, seg, outT);
    // 6) out = outT^T: in [16384][1024] -> out [1024][16384]
    transpose_v4<<<dim3(N_ROWS / 64, F_DIM / 64), 256, 0, stream>>>(
        outT, out, F_DIM, N_ROWS);
}

// Round 2
// 343.228 us; speedup vs baseline: 1.0163x; 1.0135x over previous
//
#include <hip/hip_runtime.h>
#include <hip/hip_bf16.h>

#define D_DIM 768
#define F_DIM 16384
#define M_CONN 262144
#define N_ROWS 1024   // B*S = 2*512

typedef float f32x4 __attribute__((ext_vector_type(4)));

__device__ __forceinline__ float bf2f(unsigned short u) {
    return __uint_as_float(((unsigned int)u) << 16);
}

// ---------------------------------------------------------------------------
// Vectorized fp32 -> fp32 transpose: in [R][C] -> out [C][R].
// 64x64 tile, 256 threads. float4 loads/stores. Nontemporal both ways
// (this kernel is only used for the final outT -> out, both streams are
// touch-once).
// Grid: dim3(C/64, R/64).
// ---------------------------------------------------------------------------
__global__ __launch_bounds__(256) void transpose_v4(const float* __restrict__ in,
                                                    float* __restrict__ out,
                                                    int R, int C) {
    __shared__ float tile[64][66];
    const int t = threadIdx.x;
    const int x0 = blockIdx.x * 64;  // col origin in `in`
    const int y0 = blockIdx.y * 64;  // row origin in `in`
#pragma unroll
    for (int k = 0; k < 4; ++k) {
        const int idx = k * 256 + t;
        const int r = idx >> 4, c4 = idx & 15;
        const f32x4 v = __builtin_nontemporal_load(
            (const f32x4*)(in + (size_t)(y0 + r) * C + x0 + c4 * 4));
        float* p = &tile[r][c4 * 4];
        p[0] = v.x; p[1] = v.y; p[2] = v.z; p[3] = v.w;
    }
    __syncthreads();
#pragma unroll
    for (int k = 0; k < 4; ++k) {
        const int idx = k * 256 + t;
        const int c = idx >> 4, r4 = idx & 15;  // out row = x0+c, out cols y0+4r4..+3
        f32x4 o;
        o.x = tile[r4 * 4 + 0][c];
        o.y = tile[r4 * 4 + 1][c];
        o.z = tile[r4 * 4 + 2][c];
        o.w = tile[r4 * 4 + 3][c];
        __builtin_nontemporal_store(o, (f32x4*)(out + (size_t)(x0 + c) * R + y0 + r4 * 4));
    }
}

// ---------------------------------------------------------------------------
// Vectorized fp32 -> bf16 transpose: in [R][C] fp32 -> out [C][R] bf16.
// Nontemporal loads (input touched once); stores stay cached (udT/upT are
// consumed by the immediately-following gather kernel).
// Grid: dim3(C/64, R/64).
// ---------------------------------------------------------------------------
__global__ __launch_bounds__(256) void transpose_f2b_v4(const float* __restrict__ in,
                                                        unsigned short* __restrict__ out,
                                                        int R, int C) {
    __shared__ float tile[64][66];
    const int t = threadIdx.x;
    const int x0 = blockIdx.x * 64;
    const int y0 = blockIdx.y * 64;
#pragma unroll
    for (int k = 0; k < 4; ++k) {
        const int idx = k * 256 + t;
        const int r = idx >> 4, c4 = idx & 15;
        const f32x4 v = __builtin_nontemporal_load(
            (const f32x4*)(in + (size_t)(y0 + r) * C + x0 + c4 * 4));
        float* p = &tile[r][c4 * 4];
        p[0] = v.x; p[1] = v.y; p[2] = v.z; p[3] = v.w;
    }
    __syncthreads();
#pragma unroll
    for (int k = 0; k < 4; ++k) {
        const int idx = k * 256 + t;
        const int c = idx >> 4, r4 = idx & 15;
        __hip_bfloat16 b0 = __float2bfloat16(tile[r4 * 4 + 0][c]);
        __hip_bfloat16 b1 = __float2bfloat16(tile[r4 * 4 + 1][c]);
        __hip_bfloat16 b2 = __float2bfloat16(tile[r4 * 4 + 2][c]);
        __hip_bfloat16 b3 = __float2bfloat16(tile[r4 * 4 + 3][c]);
        ushort4 o;
        o.x = *(unsigned short*)&b0;
        o.y = *(unsigned short*)&b1;
        o.z = *(unsigned short*)&b2;
        o.w = *(unsigned short*)&b3;
        *(ushort4*)(out + (size_t)(x0 + c) * R + y0 + r4 * 4) = o;
    }
}

// ---------------------------------------------------------------------------
// values[m] = dot(de[i_m, :], udT[j_m, :]) over D=768, udT in bf16.
// One wave per 4 consecutive m. All 4 connections' udT rows are prefetched
// up front (12 independent ushort4 gathers in flight) before the serial
// dot/reduce chain; sorted i -> de row register-cached across m.
// ---------------------------------------------------------------------------
__global__ __launch_bounds__(256) void values_kernel(const float* __restrict__ de,
                                                     const unsigned short* __restrict__ udT,
                                                     const int* __restrict__ i_idx,
                                                     const int* __restrict__ j_idx,
                                                     float* __restrict__ values) {
    const int wave = (blockIdx.x * blockDim.x + threadIdx.x) >> 6;
    const int lane = threadIdx.x & 63;
    const int mbase = wave * 4;

    int ii[4], jj[4];
#pragma unroll
    for (int t = 0; t < 4; ++t) {
        ii[t] = i_idx[mbase + t];
        jj[t] = j_idx[mbase + t];
    }
    ushort4 u[4][3];
#pragma unroll
    for (int t = 0; t < 4; ++t) {
        const ushort4* b = (const ushort4*)(udT + (size_t)jj[t] * D_DIM);
        u[t][0] = b[lane]; u[t][1] = b[lane + 64]; u[t][2] = b[lane + 128];
    }

    int cur_i = -1;
    float4 a0, a1, a2;
#pragma unroll
    for (int t = 0; t < 4; ++t) {
        const int i = ii[t];
        if (i != cur_i) {  // wave-uniform (i uniform across lanes)
            const float4* a = (const float4*)(de + (size_t)i * D_DIM);
            a0 = a[lane]; a1 = a[lane + 64]; a2 = a[lane + 128];
            cur_i = i;
        }
        float s = 0.f;
        s = fmaf(a0.x, bf2f(u[t][0].x), s); s = fmaf(a0.y, bf2f(u[t][0].y), s);
        s = fmaf(a0.z, bf2f(u[t][0].z), s); s = fmaf(a0.w, bf2f(u[t][0].w), s);
        s = fmaf(a1.x, bf2f(u[t][1].x), s); s = fmaf(a1.y, bf2f(u[t][1].y), s);
        s = fmaf(a1.z, bf2f(u[t][1].z), s); s = fmaf(a1.w, bf2f(u[t][1].w), s);
        s = fmaf(a2.x, bf2f(u[t][2].x), s); s = fmaf(a2.y, bf2f(u[t][2].y), s);
        s = fmaf(a2.z, bf2f(u[t][2].z), s); s = fmaf(a2.w, bf2f(u[t][2].w), s);
#pragma unroll
        for (int off = 32; off > 0; off >>= 1)
            s += __shfl_down(s, off, 64);
        if (lane == 0) values[mbase + t] = s;
    }
}

// ---------------------------------------------------------------------------
// seg[i] = lower_bound(i_idx, M, i); seg[F] = M.
// ---------------------------------------------------------------------------
__global__ __launch_bounds__(256) void seg_kernel(const int* __restrict__ i_idx,
                                                  int* __restrict__ seg) {
    const int i = blockIdx.x * blockDim.x + threadIdx.x;
    if (i > F_DIM) return;
    if (i == F_DIM) { seg[i] = M_CONN; return; }
    int lo = 0, hi = M_CONN;
    while (lo < hi) {
        int mid = (lo + hi) >> 1;
        if (i_idx[mid] < i) lo = mid + 1; else hi = mid;
    }
    seg[i] = lo;
}

// ---------------------------------------------------------------------------
// SpMM, transposed layout, bf16 rows: outT[i,:] = sum_m v_m * upT[j_m,:].
// One 256-thread block per i; 4-way connection unroll = 4 independent 8-B
// gathers in flight per thread; fp32 acc; NONTEMPORAL outT store so the
// 64 MB output stream does not evict upT (32 MB, 16x reuse) from L2.
// ---------------------------------------------------------------------------
__global__ __launch_bounds__(256) void spmm_kernel(const unsigned short* __restrict__ upT,
                                                   const int* __restrict__ j_idx,
                                                   const float* __restrict__ vals,
                                                   const int* __restrict__ seg,
                                                   float* __restrict__ outT) {
    const int i = blockIdx.x;
    const int t = threadIdx.x;
    const int ms = seg[i], me = seg[i + 1];
    float4 acc0 = make_float4(0.f, 0.f, 0.f, 0.f);
    float4 acc1 = make_float4(0.f, 0.f, 0.f, 0.f);
    float4 acc2 = make_float4(0.f, 0.f, 0.f, 0.f);
    float4 acc3 = make_float4(0.f, 0.f, 0.f, 0.f);
    int m = ms;
    for (; m + 3 < me; m += 4) {
        const int j0 = j_idx[m],     j1 = j_idx[m + 1];
        const int j2 = j_idx[m + 2], j3 = j_idx[m + 3];
        const float v0 = vals[m],     v1 = vals[m + 1];
        const float v2 = vals[m + 2], v3 = vals[m + 3];
        const ushort4 x0 = ((const ushort4*)(upT + (size_t)j0 * N_ROWS))[t];
        const ushort4 x1 = ((const ushort4*)(upT + (size_t)j1 * N_ROWS))[t];
        const ushort4 x2 = ((const ushort4*)(upT + (size_t)j2 * N_ROWS))[t];
        const ushort4 x3 = ((const ushort4*)(upT + (size_t)j3 * N_ROWS))[t];
        acc0.x = fmaf(v0, bf2f(x0.x), acc0.x); acc0.y = fmaf(v0, bf2f(x0.y), acc0.y);
        acc0.z = fmaf(v0, bf2f(x0.z), acc0.z); acc0.w = fmaf(v0, bf2f(x0.w), acc0.w);
        acc1.x = fmaf(v1, bf2f(x1.x), acc1.x); acc1.y = fmaf(v1, bf2f(x1.y), acc1.y);
        acc1.z = fmaf(v1, bf2f(x1.z), acc1.z); acc1.w = fmaf(v1, bf2f(x1.w), acc1.w);
        acc2.x = fmaf(v2, bf2f(x2.x), acc2.x); acc2.y = fmaf(v2, bf2f(x2.y), acc2.y);
        acc2.z = fmaf(v2, bf2f(x2.z), acc2.z); acc2.w = fmaf(v2, bf2f(x2.w), acc2.w);
        acc3.x = fmaf(v3, bf2f(x3.x), acc3.x); acc3.y = fmaf(v3, bf2f(x3.y), acc3.y);
        acc3.z = fmaf(v3, bf2f(x3.z), acc3.z); acc3.w = fmaf(v3, bf2f(x3.w), acc3.w);
    }
    for (; m < me; ++m) {
        const int j0 = j_idx[m];
        const float v0 = vals[m];
        const ushort4 x0 = ((const ushort4*)(upT + (size_t)j0 * N_ROWS))[t];
        acc0.x = fmaf(v0, bf2f(x0.x), acc0.x); acc0.y = fmaf(v0, bf2f(x0.y), acc0.y);
        acc0.z = fmaf(v0, bf2f(x0.z), acc0.z); acc0.w = fmaf(v0, bf2f(x0.w), acc0.w);
    }
    f32x4 r;
    r.x = (acc0.x + acc1.x) + (acc2.x + acc3.x);
    r.y = (acc0.y + acc1.y) + (acc2.y + acc3.y);
    r.z = (acc0.z + acc1.z) + (acc2.z + acc3.z);
    r.w = (acc0.w + acc1.w) + (acc2.w + acc3.w);
    __builtin_nontemporal_store(r, (f32x4*)(outT + (size_t)i * N_ROWS) + t);
}

// ---------------------------------------------------------------------------
// Buffer plan (ws ~65.1 MB):
//   ws + 0     : udT bf16 [F,D] 24 MB (stages 1-2), then outT fp32 [F,1024] 64 MB
//   ws + 64 MB : values [M] fp32, 1 MB
//   ws + 65 MB : seg [F+1] int, 64 KB
//   d_out      : upT bf16 [F,1024] 32 MB (stages 3-5), then final out fp32
// ---------------------------------------------------------------------------
extern "C" void kernel_launch(void* const* d_in, const int* in_sizes, int n_in,
                              void* d_out, int out_size, void* d_ws, size_t ws_size,
                              hipStream_t stream) {
    const float* up_facts = (const float*)d_in[0];   // [1024, F]
    const float* de       = (const float*)d_in[1];   // [F, D]
    const float* ud       = (const float*)d_in[2];   // [D, F]
    const int*   i_idx    = (const int*)d_in[3];     // [M] sorted
    const int*   j_idx    = (const int*)d_in[4];     // [M]
    float* out = (float*)d_out;

    char* ws = (char*)d_ws;
    unsigned short* udT = (unsigned short*)ws;                     // bf16 [F, D]
    float* outT   = (float*)ws;                                    // fp32 [F, 1024] (udT dead)
    float* values = (float*)(ws + (size_t)64 * 1024 * 1024);       // 1 MB
    int*   seg    = (int*)  (ws + (size_t)65 * 1024 * 1024);       // 64 KB + 4
    unsigned short* upT = (unsigned short*)out;                    // bf16 [F, 1024]

    // 1) udT = bf16(ud^T): in [768][16384] -> out [16384][768]
    transpose_f2b_v4<<<dim3(F_DIM / 64, D_DIM / 64), 256, 0, stream>>>(
        ud, udT, D_DIM, F_DIM);
    // 2) values[m] = <de[i_m], udT[j_m]>
    values_kernel<<<(M_CONN / 4) * 64 / 256, 256, 0, stream>>>(de, udT, i_idx, j_idx, values);
    // 3) upT = bf16(up_facts^T): in [1024][16384] -> out [16384][1024]
    transpose_f2b_v4<<<dim3(F_DIM / 64, N_ROWS / 64), 256, 0, stream>>>(
        up_facts, upT, N_ROWS, F_DIM);
    // 4) CSR row pointers
    seg_kernel<<<(F_DIM + 1 + 255) / 256, 256, 0, stream>>>(i_idx, seg);
    // 5) outT[i] = sum v * upT[j]
    spmm_kernel<<<F_DIM, 256, 0, stream>>>(upT, j_idx, values, seg, outT);
    // 6) out = outT^T: in [16384][1024] -> out [1024][16384]
    transpose_v4<<<dim3(N_ROWS / 64, F_DIM / 64), 256, 0, stream>>>(
        outT, out, F_DIM, N_ROWS);
}